// Round 12
// baseline (703.238 us; speedup 1.0000x reference)
//
#include <hip/hip_runtime.h>
#include <hip/hip_bf16.h>
#include <math.h>

// Problem constants (from reference)
constexpr int cN   = 10000;
constexpr int cE   = 120000;
constexpr int cFin = 64;
constexpr int cC   = 128;
constexpr int cH   = 4;
constexpr int cL   = 5;
constexpr int cG   = 500;
constexpr int cOUT = 1801;
constexpr int cHL  = 320;          // (L*C)/2
constexpr int c4HL = 4 * cHL;      // 1280
constexpr int cP   = 2 * c4HL;     // 2560 (fwd|bwd gate cols)

typedef short bf16x8 __attribute__((ext_vector_type(8)));
typedef float f32x4 __attribute__((ext_vector_type(4)));

__device__ inline unsigned short f2b(float x) {
    union { __hip_bfloat16 h; unsigned short u; } cv;
    cv.h = __float2bfloat16(x);
    return cv.u;
}
__device__ inline float b2f(unsigned short u) {
    union { unsigned int i; float f; } cv;
    cv.i = ((unsigned int)u) << 16;
    return cv.f;
}
__device__ inline float fsig(float x)  { return 1.f / (1.f + __expf(-x)); }
__device__ inline float ftanh(float x) { return 1.f - 2.f / (__expf(2.f * x) + 1.f); }

#define GLD16(g, l) __builtin_amdgcn_global_load_lds( \
    (const __attribute__((address_space(1))) unsigned int*)(g), \
    (__attribute__((address_space(3))) unsigned int*)(l), 16, 0, 0)

// ---------------- utility kernels ----------------
__global__ void fill_i32_kernel(int* __restrict__ p, long n, int v) {
    long i = (long)blockIdx.x * blockDim.x + threadIdx.x;
    if (i < n) p[i] = v;
}
__global__ void copy_i32_kernel(const int* __restrict__ a, int* __restrict__ b, long n) {
    long i = (long)blockIdx.x * blockDim.x + threadIdx.x;
    if (i < n) b[i] = a[i];
}
__global__ void conv_bf16_kernel(const float* __restrict__ a, unsigned short* __restrict__ b, long n) {
    long i = (long)blockIdx.x * blockDim.x + threadIdx.x;
    if (i < n) b[i] = f2b(a[i]);
}
// zero jks(50000) | pooled(64000) | cnt(500) in one launch
__global__ void init_tail_kernel(float* __restrict__ jks, float* __restrict__ pooled,
                                 float* __restrict__ cnt) {
    long i = (long)blockIdx.x * blockDim.x + threadIdx.x;
    if (i < (long)cL * cN) jks[i] = 0.f;
    else if (i < (long)cL * cN + cG * cC) pooled[i - (long)cL * cN] = 0.f;
    else if (i < (long)cL * cN + cG * cC + cG) cnt[i - (long)cL * cN - cG * cC] = 0.f;
}
// Wl,Wr: [L][128][512] fp32 -> WT: [L][1024][128] bf16 (rows 0..511 = Wl^T, 512..1023 = Wr^T)
__global__ void wproj_prep_kernel(const float* __restrict__ Wl, const float* __restrict__ Wr,
                                  unsigned short* __restrict__ WT) {
    long i = (long)blockIdx.x * blockDim.x + threadIdx.x;
    if (i >= (long)cL * 1024 * 128) return;
    int k = i & 127;
    int n = (int)((i >> 7) & 1023);
    int l = (int)(i >> 17);
    const float* W = (n < 512) ? Wl : Wr;
    int nn = n & 511;
    WT[i] = f2b(W[(size_t)l * 65536 + (size_t)k * 512 + nn]);
}
// bl,br: [L][512] -> bb: [L][1024]
__global__ void bias_prep_kernel(const float* __restrict__ bl, const float* __restrict__ br,
                                 float* __restrict__ bb) {
    int i = blockIdx.x * blockDim.x + threadIdx.x;
    if (i >= cL * 1024) return;
    int n = i & 1023, l = i >> 10;
    bb[i] = (n < 512) ? bl[l * 512 + n] : br[l * 512 + (n - 512)];
}
// emb_W: [64][128] fp32 (KxN) -> embWT: [128][64] bf16 (NxK)
__global__ void embw_prep_kernel(const float* __restrict__ W, unsigned short* __restrict__ WT) {
    int i = blockIdx.x * blockDim.x + threadIdx.x;
    if (i >= cC * cFin) return;
    int k = i & 63, n = i >> 6;
    WT[i] = f2b(W[(size_t)k * cC + n]);
}
// LSTM weights -> gate-interleaved rows: p = (u>>4)*64 + g*16 + (u&15), r = g*320+u
__global__ void lstm_prep_kernel(const float* __restrict__ Wih, const float* __restrict__ Whh,
                                 const float* __restrict__ bih, const float* __restrict__ bhh,
                                 unsigned short* __restrict__ WihP, unsigned short* __restrict__ WhhP,
                                 float* __restrict__ biasP) {
    long i = (long)blockIdx.x * blockDim.x + threadIdx.x;   // over 1280*449
    if (i >= (long)c4HL * 449) return;
    int p = (int)(i / 449), c = (int)(i % 449);
    int u = (p >> 6) * 16 + (p & 15);
    int g = (p >> 4) & 3;
    int r = g * cHL + u;
    if (c < cC)       WihP[(size_t)p * cC + c] = f2b(Wih[(size_t)r * cC + c]);
    else if (c < 448) WhhP[(size_t)p * cHL + (c - cC)] = f2b(Whh[(size_t)r * cHL + (c - cC)]);
    else              biasP[p] = bih[r] + bhh[r];
}

// ---------------- CSR build (by dst), payload = src node ----------------
__global__ void hist_kernel(const int* __restrict__ dst, int* __restrict__ count) {
    int i = blockIdx.x * blockDim.x + threadIdx.x;
    if (i < cE) atomicAdd(&count[dst[i]], 1);
}
__global__ void scan_kernel(const int* __restrict__ count, int* __restrict__ offs) {
    __shared__ int part[256];
    const int tid = threadIdx.x;
    const int CH = (cN + 255) / 256;
    int base = tid * CH;
    int s = 0;
    for (int i = 0; i < CH; i++) {
        int idx = base + i;
        if (idx < cN) s += count[idx];
    }
    part[tid] = s;
    __syncthreads();
    for (int d = 1; d < 256; d <<= 1) {
        int v = 0;
        if (tid >= d) v = part[tid - d];
        __syncthreads();
        if (tid >= d) part[tid] += v;
        __syncthreads();
    }
    int prefix = (tid == 0) ? 0 : part[tid - 1];
    for (int i = 0; i < CH; i++) {
        int idx = base + i;
        if (idx < cN) { offs[idx] = prefix; prefix += count[idx]; }
    }
    if (tid == 255) offs[cN] = prefix;
}
__global__ void scatter_kernel(const int* __restrict__ src, const int* __restrict__ dst,
                               int* __restrict__ cursor, int* __restrict__ src_csr) {
    int i = blockIdx.x * blockDim.x + threadIdx.x;
    if (i < cE) {
        int pos = atomicAdd(&cursor[dst[i]], 1);
        src_csr[pos] = src[i];
    }
}

// ---------------- bf16 MFMA GEMM (128x128, 4 waves) ----------------
// SWZ=1: 1D grid, XCD-aware group swizzle.
template<int HASBIAS, int OUTB, int SWZ>
__global__ __launch_bounds__(256)
void gemm_mfma_kernel(const unsigned short* __restrict__ A1, const unsigned short* __restrict__ B1, int k1,
                      const unsigned short* __restrict__ A2, const unsigned short* __restrict__ B2, int k2,
                      const float* __restrict__ bias, void* __restrict__ Cout, int M, int N, int nbn) {
    int bm, bn;
    if (SWZ) {
        int bid = blockIdx.x;
        int xcd = bid & 7, j = bid >> 3;
        int g   = (j / nbn) * 8 + xcd;
        bm = g << 7;
        bn = (j % nbn) << 7;
        if (bm >= M) return;   // padded group: whole block exits (pre-barrier)
    } else {
        bm = blockIdx.y << 7;
        bn = blockIdx.x << 7;
    }
    __shared__ unsigned short lds[2][2][128 * 32];
    const int tid  = threadIdx.x;
    const int lane = tid & 63;
    const int wave = tid >> 6;
    const int wr = (wave >> 1) << 6;
    const int wc = (wave & 1) << 6;
    const int ns1 = k1 >> 5, ns2 = k2 >> 5, ns = ns1 + ns2;

    const int lrow = lane >> 2;
    const int lke  = (lane & 3) << 3;

    auto stage = [&](int s, int buf) {
        const unsigned short *Ab, *Bb;
        int stride, koff;
        if (s < ns1) { Ab = A1; Bb = B1; stride = k1; koff = s << 5; }
        else         { Ab = A2; Bb = B2; stride = k2; koff = (s - ns1) << 5; }
#pragma unroll
        for (int r = 0; r < 2; r++) {
            int ch  = wave * 2 + r;
            int row = ch * 16 + lrow;
            int ga  = bm + row; if (ga >= M) ga = M - 1;
            GLD16(Ab + (size_t)ga * stride + koff + lke, &lds[buf][0][ch * 512]);
            GLD16(Bb + (size_t)(bn + row) * stride + koff + lke, &lds[buf][1][ch * 512]);
        }
    };

    f32x4 acc[4][4];
#pragma unroll
    for (int i = 0; i < 4; i++)
#pragma unroll
        for (int j = 0; j < 4; j++) acc[i][j] = (f32x4){0.f, 0.f, 0.f, 0.f};

    stage(0, 0);
    const int ko  = (lane >> 4) << 3;
    const int rla = lane & 15;
    for (int s = 0; s < ns; s++) {
        int buf = s & 1;
        __syncthreads();
        if (s + 1 < ns) stage(s + 1, buf ^ 1);
        bf16x8 af[4], bff[4];
#pragma unroll
        for (int f = 0; f < 4; f++) {
            af[f]  = *(const bf16x8*)&lds[buf][0][(wr + f * 16 + rla) * 32 + ko];
            bff[f] = *(const bf16x8*)&lds[buf][1][(wc + f * 16 + rla) * 32 + ko];
        }
#pragma unroll
        for (int i = 0; i < 4; i++)
#pragma unroll
            for (int j = 0; j < 4; j++)
                acc[i][j] = __builtin_amdgcn_mfma_f32_16x16x32_bf16(af[i], bff[j], acc[i][j], 0, 0, 0);
    }

#pragma unroll
    for (int i = 0; i < 4; i++) {
#pragma unroll
        for (int v = 0; v < 4; v++) {
            int m = bm + wr + i * 16 + ((lane >> 4) << 2) + v;
            if (m < M) {
#pragma unroll
                for (int j = 0; j < 4; j++) {
                    int n = bn + wc + j * 16 + rla;
                    float val = acc[i][j][v];
                    if (HASBIAS) val += bias[n];
                    if (OUTB) ((unsigned short*)Cout)[(size_t)m * N + n] = f2b(val);
                    else      ((float*)Cout)[(size_t)m * N + n] = val;
                }
            }
        }
    }
}

// ---------------- dual-direction LSTM step: 128x256 tile, 8 waves -----------
// USEP=1: Wih contribution precomputed in P; GEMM runs only K=320 (h @ Whh^T).
template<int FIRST, int USEP>
__global__ __launch_bounds__(512)
void gemm_lstm_dual_kernel(const unsigned short* __restrict__ A1f, const unsigned short* __restrict__ A1b,
                           const unsigned short* __restrict__ Bihf, const unsigned short* __restrict__ Bihb,
                           const unsigned short* __restrict__ A2f, const unsigned short* __restrict__ A2b,
                           const unsigned short* __restrict__ Bhhf, const unsigned short* __restrict__ Bhhb,
                           const float* __restrict__ biasPf, const float* __restrict__ biasPb,
                           float* __restrict__ cff, float* __restrict__ cbb,
                           unsigned short* __restrict__ hOutf, unsigned short* __restrict__ hOutb,
                           const float* __restrict__ jkw,
                           float* __restrict__ scoref, float* __restrict__ scoreb,
                           const unsigned short* __restrict__ PfP, const unsigned short* __restrict__ PbP) {
    constexpr int M = cN;
    constexpr int k1 = USEP ? 0 : cC;
    constexpr int k2 = FIRST ? 0 : cHL;
    const int bid = blockIdx.x;
    const int xcd = bid & 7, jj = bid >> 3;
    const int g     = (jj / 10) * 8 + xcd;
    const int inner = jj % 10;
    const int bm = g << 7;
    if (bm >= M) return;                 // padded group: uniform pre-barrier exit
    const int bn = (inner % 5) << 8;     // 0..1024 step 256
    const int z  = inner / 5;

    const unsigned short* A1 = z ? A1b : A1f;
    const unsigned short* B1 = z ? Bihb : Bihf;
    const unsigned short* A2 = z ? A2b : A2f;
    const unsigned short* B2 = z ? Bhhb : Bhhf;
    const float* biasP = z ? biasPb : biasPf;
    float* cbuf = z ? cbb : cff;
    unsigned short* hOut = z ? hOutb : hOutf;
    const float* jkwz = jkw + (z ? cHL : 0);
    float* score_t = z ? scoreb : scoref;
    const unsigned short* Pst = z ? PbP : PfP;
    const int pcb = (z ? c4HL : 0) + bn;

    __shared__ unsigned short ldsA[2][128 * 32];
    __shared__ unsigned short ldsB[2][256 * 32];
    const int tid  = threadIdx.x;
    const int lane = tid & 63;
    const int wave = tid >> 6;           // 0..7
    const int wr = (wave >> 2) << 6;     // 0 or 64
    const int wc = (wave & 3) << 6;      // 0,64,128,192
    const int ns1 = k1 >> 5, ns2 = k2 >> 5, ns = ns1 + ns2;

    const int lrow = lane >> 2;
    const int lke  = (lane & 3) << 3;

    auto stage = [&](int s, int buf) {
        const unsigned short *Ab, *Bb;
        int stride, koff;
        if (s < ns1) { Ab = A1; Bb = B1; stride = k1; koff = s << 5; }
        else         { Ab = A2; Bb = B2; stride = k2; koff = (s - ns1) << 5; }
        {
            int row = wave * 16 + lrow;
            int ga  = bm + row; if (ga >= M) ga = M - 1;
            GLD16(Ab + (size_t)ga * stride + koff + lke, &ldsA[buf][wave * 512]);
        }
#pragma unroll
        for (int r = 0; r < 2; r++) {
            int ch  = wave * 2 + r;
            int row = ch * 16 + lrow;
            GLD16(Bb + (size_t)(bn + row) * stride + koff + lke, &ldsB[buf][ch * 512]);
        }
    };

    f32x4 acc[4][4];
#pragma unroll
    for (int i = 0; i < 4; i++)
#pragma unroll
        for (int j = 0; j < 4; j++) acc[i][j] = (f32x4){0.f, 0.f, 0.f, 0.f};

    if (ns > 0) stage(0, 0);
    const int ko  = (lane >> 4) << 3;
    const int rla = lane & 15;
    for (int s = 0; s < ns; s++) {
        int buf = s & 1;
        __syncthreads();
        if (s + 1 < ns) stage(s + 1, buf ^ 1);
        bf16x8 af[4], bff[4];
#pragma unroll
        for (int f = 0; f < 4; f++) {
            af[f]  = *(const bf16x8*)&ldsA[buf][(wr + f * 16 + rla) * 32 + ko];
            bff[f] = *(const bf16x8*)&ldsB[buf][(wc + f * 16 + rla) * 32 + ko];
        }
#pragma unroll
        for (int i = 0; i < 4; i++)
#pragma unroll
            for (int j = 0; j < 4; j++)
                acc[i][j] = __builtin_amdgcn_mfma_f32_16x16x32_bf16(af[i], bff[j], acc[i][j], 0, 0, 0);
    }

    // gate-fused epilogue (fast sigmoid/tanh via v_exp_f32)
    float bias4[4];
#pragma unroll
    for (int j = 0; j < 4; j++) bias4[j] = biasP[bn + wc + j * 16 + rla];
    const int u = ((bn + wc) >> 6) * 16 + rla;
    const float jw = jkwz[u];

#pragma unroll
    for (int i = 0; i < 4; i++) {
#pragma unroll
        for (int v = 0; v < 4; v++) {
            int m = bm + wr + i * 16 + ((lane >> 4) << 2) + v;
            bool ok = (m < M);                      // uniform across rla group
            float p4[4] = {0.f, 0.f, 0.f, 0.f};
            if (USEP) {
                int mp = ok ? m : M - 1;            // clamp padded rows
#pragma unroll
                for (int j = 0; j < 4; j++)
                    p4[j] = b2f(Pst[(size_t)mp * cP + pcb + wc + j * 16 + rla]);
            }
            float gi = acc[i][0][v] + p4[0] + bias4[0];
            float gf = acc[i][1][v] + p4[1] + bias4[1];
            float gg = acc[i][2][v] + p4[2] + bias4[2];
            float go = acc[i][3][v] + p4[3] + bias4[3];
            float si = fsig(gi);
            float sf = fsig(gf);
            float so = fsig(go);
            float tg = ftanh(gg);
            size_t idx = (size_t)m * cHL + u;
            float cold = (FIRST || !ok) ? 0.f : cbuf[idx];
            float cc = sf * cold + si * tg;
            float hh = so * ftanh(cc);
            if (ok) { cbuf[idx] = cc; hOut[idx] = f2b(hh); }
            float part = ok ? hh * jw : 0.f;
#pragma unroll
            for (int o = 1; o < 16; o <<= 1) part += __shfl_xor(part, o);
            if (rla == 0 && ok) atomicAdd(&score_t[m], part);
        }
    }
}

// ---------------- fused GAT layer: 2 waves per node, split edge list --------
// block = 256 = 2 nodes x 2 waves. Each wave runs the 4-edge-unrolled online
// softmax over its half of the CSR range; exact state merge via LDS; wave
// half==0 finishes heads-mean + LN and stores bf16.
__global__ __launch_bounds__(256)
void gat_fused_kernel(const unsigned short* __restrict__ xlr, const int* __restrict__ src_csr,
                      const int* __restrict__ offs, const float* __restrict__ att,
                      const float* __restrict__ conv_b, const float* __restrict__ lnw,
                      const float* __restrict__ lnb, unsigned short* __restrict__ seqb_l) {
    __shared__ float smacc[2][512];
    __shared__ float smm[2][4];
    __shared__ float sml[2][4];
    const int tid  = threadIdx.x;
    const int wave = tid >> 6;           // 0..3
    const int lane = tid & 63;
    const int nl   = wave >> 1;          // node-local 0/1
    const int half = wave & 1;
    const int wv   = blockIdx.x * 2 + nl;   // grid 5000 -> wv < 10000 always
    const int h    = lane >> 4;
    const int cb   = (lane & 15) << 3;

    bf16x8 xrv = *(const bf16x8*)&xlr[(size_t)wv * 1024 + 512 + lane * 8];
    float xr[8], av[8];
#pragma unroll
    for (int k = 0; k < 8; k++) {
        xr[k] = b2f((unsigned short)xrv[k]);
        av[k] = att[h * 128 + cb + k];
    }

    float m = -INFINITY, l = 0.f;
    float acc[8];
#pragma unroll
    for (int k = 0; k < 8; k++) acc[k] = 0.f;

    const int beg0 = offs[wv], end0 = offs[wv + 1];
    const int midc = (end0 - beg0 + 1) >> 1;
    int j   = half ? beg0 + midc : beg0;
    const int end = half ? end0 : beg0 + midc;

    // 4-edge pipelined online softmax over this wave's half
    for (; j + 3 < end; j += 4) {
        int s0 = src_csr[j], s1 = src_csr[j + 1], s2 = src_csr[j + 2], s3 = src_csr[j + 3];
        bf16x8 xv0 = *(const bf16x8*)&xlr[(size_t)s0 * 1024 + lane * 8];
        bf16x8 xv1 = *(const bf16x8*)&xlr[(size_t)s1 * 1024 + lane * 8];
        bf16x8 xv2 = *(const bf16x8*)&xlr[(size_t)s2 * 1024 + lane * 8];
        bf16x8 xv3 = *(const bf16x8*)&xlr[(size_t)s3 * 1024 + lane * 8];
        float x0[8], x1[8], x2[8], x3[8];
        float sc0 = 0.f, sc1 = 0.f, sc2 = 0.f, sc3 = 0.f;
#pragma unroll
        for (int k = 0; k < 8; k++) {
            x0[k] = b2f((unsigned short)xv0[k]);
            x1[k] = b2f((unsigned short)xv1[k]);
            x2[k] = b2f((unsigned short)xv2[k]);
            x3[k] = b2f((unsigned short)xv3[k]);
            float v0 = x0[k] + xr[k]; v0 = v0 > 0.f ? v0 : 0.2f * v0;
            float v1 = x1[k] + xr[k]; v1 = v1 > 0.f ? v1 : 0.2f * v1;
            float v2 = x2[k] + xr[k]; v2 = v2 > 0.f ? v2 : 0.2f * v2;
            float v3 = x3[k] + xr[k]; v3 = v3 > 0.f ? v3 : 0.2f * v3;
            sc0 = fmaf(v0, av[k], sc0);
            sc1 = fmaf(v1, av[k], sc1);
            sc2 = fmaf(v2, av[k], sc2);
            sc3 = fmaf(v3, av[k], sc3);
        }
#pragma unroll
        for (int o = 1; o < 16; o <<= 1) {
            sc0 += __shfl_xor(sc0, o);
            sc1 += __shfl_xor(sc1, o);
            sc2 += __shfl_xor(sc2, o);
            sc3 += __shfl_xor(sc3, o);
        }
        float mn = fmaxf(fmaxf(fmaxf(sc0, sc1), fmaxf(sc2, sc3)), m);
        float r  = __expf(m - mn);
        float p0 = __expf(sc0 - mn);
        float p1 = __expf(sc1 - mn);
        float p2 = __expf(sc2 - mn);
        float p3 = __expf(sc3 - mn);
        l = l * r + p0 + p1 + p2 + p3;
#pragma unroll
        for (int k = 0; k < 8; k++)
            acc[k] = fmaf(acc[k], r,
                          fmaf(p0, x0[k], fmaf(p1, x1[k], fmaf(p2, x2[k], p3 * x3[k]))));
        m = mn;
    }
    for (; j < end; j++) {   // 1-3 edge tail
        int s0 = src_csr[j];
        bf16x8 xv = *(const bf16x8*)&xlr[(size_t)s0 * 1024 + lane * 8];
        float x[8], sc = 0.f;
#pragma unroll
        for (int k = 0; k < 8; k++) {
            x[k] = b2f((unsigned short)xv[k]);
            float v = x[k] + xr[k];
            v = v > 0.f ? v : 0.2f * v;
            sc = fmaf(v, av[k], sc);
        }
#pragma unroll
        for (int o = 1; o < 16; o <<= 1) sc += __shfl_xor(sc, o);
        float mn = fmaxf(m, sc);
        float r  = __expf(m - mn);
        float p  = __expf(sc - mn);
        l = l * r + p;
#pragma unroll
        for (int k = 0; k < 8; k++) acc[k] = fmaf(acc[k], r, p * x[k]);
        m = mn;
    }

    // ---- merge the two halves (exact online-softmax state combine) ----
    if (half) {
#pragma unroll
        for (int k = 0; k < 8; k++) smacc[nl][lane * 8 + k] = acc[k];
        if ((lane & 15) == 0) { smm[nl][h] = m; sml[nl][h] = l; }
    }
    __syncthreads();
    if (half) return;
    float m1 = smm[nl][h], l1 = sml[nl][h];
    float M  = fmaxf(m, m1);
    float w0 = (m  > -INFINITY) ? __expf(m  - M) : 0.f;
    float w1 = (m1 > -INFINITY) ? __expf(m1 - M) : 0.f;
    l = l * w0 + l1 * w1;
#pragma unroll
    for (int k = 0; k < 8; k++)
        acc[k] = acc[k] * w0 + smacc[nl][lane * 8 + k] * w1;

    float inv = 1.f / (l + 1e-16f);
#pragma unroll
    for (int k = 0; k < 8; k++) {
        float v = acc[k] * inv;
        v += __shfl_xor(v, 16);
        v += __shfl_xor(v, 32);
        acc[k] = 0.25f * v + conv_b[cb + k];
    }
    float ssum = 0.f;
#pragma unroll
    for (int k = 0; k < 8; k++) ssum += acc[k];
#pragma unroll
    for (int o = 1; o < 16; o <<= 1) ssum += __shfl_xor(ssum, o);
    float mu = ssum * (1.f / 128.f);
    float vs = 0.f;
#pragma unroll
    for (int k = 0; k < 8; k++) { float d = acc[k] - mu; vs = fmaf(d, d, vs); }
#pragma unroll
    for (int o = 1; o < 16; o <<= 1) vs += __shfl_xor(vs, o);
    float rstd = 1.f / sqrtf(vs * (1.f / 128.f) + 1e-5f);

    float outv[8];
#pragma unroll
    for (int k = 0; k < 8; k++)
        outv[k] = (acc[k] - mu) * rstd * lnw[cb + k] + lnb[cb + k];

    if (h == 0) {
        size_t b = (size_t)wv * 128 + cb;
        bf16x8 ob;
#pragma unroll
        for (int k = 0; k < 8; k++) ob[k] = (short)f2b(outv[k]);
        *(bf16x8*)&seqb_l[b] = ob;
    }
}

// ---------------- JK softmax + mean pooling (bf16 seq) ----------------
__global__ void jk_pool_kernel(const unsigned short* __restrict__ seqb, const float* __restrict__ score,
                               const int* __restrict__ batch, float* __restrict__ pooled) {
    int wid = (blockIdx.x * blockDim.x + threadIdx.x) >> 6;
    int lane = threadIdx.x & 63;
    if (wid >= cN) return;
    float s[cL], mx = -INFINITY;
#pragma unroll
    for (int l = 0; l < cL; l++) { s[l] = score[(size_t)l * cN + wid]; mx = fmaxf(mx, s[l]); }
    float se = 0.f;
#pragma unroll
    for (int l = 0; l < cL; l++) { s[l] = __expf(s[l] - mx); se += s[l]; }
    float inv = 1.f / se;
    int g = batch[wid];
    float acc0 = 0.f, acc1 = 0.f;
#pragma unroll
    for (int l = 0; l < cL; l++) {
        const unsigned short* sp = seqb + ((size_t)l * cN + wid) * 128;
        float w = s[l] * inv;
        acc0 += w * b2f(sp[lane]);
        acc1 += w * b2f(sp[lane + 64]);
    }
    atomicAdd(&pooled[(size_t)g * 128 + lane], acc0);
    atomicAdd(&pooled[(size_t)g * 128 + lane + 64], acc1);
}

__global__ void count_kernel(const int* __restrict__ batch, float* __restrict__ cnt) {
    int i = blockIdx.x * blockDim.x + threadIdx.x;
    if (i < cN) atomicAdd(&cnt[batch[i]], 1.f);
}

__global__ void div_pool_kernel(float* __restrict__ pooled, const float* __restrict__ cnt) {
    int i = blockIdx.x * blockDim.x + threadIdx.x;
    if (i < cG * 128) pooled[i] /= fmaxf(cnt[i >> 7], 1.f);
}

// ---------------- fused MLP head ----------------
__global__ __launch_bounds__(256)
void head_fused_kernel(const float* __restrict__ pooled,
                       const float* __restrict__ m1_w, const float* __restrict__ m1_b,
                       const float* __restrict__ m2_w, const float* __restrict__ m2_b,
                       const float* __restrict__ res_w, const float* __restrict__ res_b,
                       float* __restrict__ out) {
    __shared__ float pl[4][128];
    __shared__ float hd[4][128];
    const int tid = threadIdx.x;
    const int r0 = blockIdx.y << 2;
    const int c0 = blockIdx.x << 8;
#pragma unroll
    for (int e = tid; e < 512; e += 256) {
        int r = e >> 7, k = e & 127;
        pl[r][k] = pooled[(size_t)(r0 + r) * 128 + k];
    }
    __syncthreads();
#pragma unroll
    for (int e = tid; e < 512; e += 256) {
        int r = e >> 7, n = e & 127;
        float acc = m1_b[n];
#pragma unroll 8
        for (int k = 0; k < 128; k++) acc = fmaf(pl[r][k], m1_w[k * 128 + n], acc);
        hd[r][n] = fmaxf(acc, 0.f);
    }
    __syncthreads();
    int col = c0 + tid;
    if (col >= cOUT) return;
    float b = m2_b[col] + res_b[col];
    float acc[4] = {b, b, b, b};
    for (int k = 0; k < 128; k++) {
        float w2 = m2_w[(size_t)k * cOUT + col];
        float wr = res_w[(size_t)k * cOUT + col];
#pragma unroll
        for (int r = 0; r < 4; r++)
            acc[r] = fmaf(hd[r][k], w2, fmaf(pl[r][k], wr, acc[r]));
    }
#pragma unroll
    for (int r = 0; r < 4; r++)
        out[(size_t)(r0 + r) * cOUT + col] = acc[r];
}

// ---------------- launch helpers ----------------
static inline int ceil_div(long a, long b) { return (int)((a + b - 1) / b); }

// non-swizzled (embedding: single column block)
template<int OUTB>
static void launch_mfma(const unsigned short* A1, const unsigned short* B1, int k1,
                        const unsigned short* A2, const unsigned short* B2, int k2,
                        const float* bias, void* C, int M, int N, hipStream_t s) {
    dim3 g((N + 127) >> 7, (M + 127) >> 7);
    if (bias) gemm_mfma_kernel<1, OUTB, 0><<<g, 256, 0, s>>>(A1, B1, k1, A2, B2, k2, bias, C, M, N, 0);
    else      gemm_mfma_kernel<0, OUTB, 0><<<g, 256, 0, s>>>(A1, B1, k1, A2, B2, k2, bias, C, M, N, 0);
}
// XCD-swizzled (nbn column blocks share a row panel)
template<int HASBIAS, int OUTB>
static void launch_mfma_swz(const unsigned short* A1, const unsigned short* B1, int k1,
                            const float* bias, void* C, int M, int N, hipStream_t s) {
    int nbn = N >> 7;
    int groups = ((((M + 127) >> 7) + 7) / 8) * 8;   // pad to multiple of 8
    dim3 g(groups * nbn);
    gemm_mfma_kernel<HASBIAS, OUTB, 1><<<g, 256, 0, s>>>(A1, B1, k1, nullptr, nullptr, 0, bias, C, M, N, nbn);
}

static void fillI(int* p, long n, int v, hipStream_t s) {
    fill_i32_kernel<<<ceil_div(n, 256), 256, 0, s>>>(p, n, v);
}
static void convB(const float* a, unsigned short* b, long n, hipStream_t s) {
    conv_bf16_kernel<<<ceil_div(n, 256), 256, 0, s>>>(a, b, n);
}

extern "C" void kernel_launch(void* const* d_in, const int* in_sizes, int n_in,
                              void* d_out, int out_size, void* d_ws, size_t ws_size,
                              hipStream_t stream) {
    const float* x      = (const float*)d_in[0];
    const int*   ei     = (const int*)d_in[1];
    const int*   batch  = (const int*)d_in[2];
    const float* emb_W  = (const float*)d_in[3];
    const float* emb_b  = (const float*)d_in[4];
    const float* Wl     = (const float*)d_in[5];
    const float* bl     = (const float*)d_in[6];
    const float* Wr     = (const float*)d_in[7];
    const float* br     = (const float*)d_in[8];
    const float* att_a  = (const float*)d_in[9];
    const float* conv_b = (const float*)d_in[10];
    const float* ln_w   = (const float*)d_in[11];
    const float* ln_b   = (const float*)d_in[12];
    const float* Wih_f  = (const float*)d_in[13];
    const float* Whh_f  = (const float*)d_in[14];
    const float* bih_f  = (const float*)d_in[15];
    const float* bhh_f  = (const float*)d_in[16];
    const float* Wih_b  = (const float*)d_in[17];
    const float* Whh_b  = (const float*)d_in[18];
    const float* bih_b  = (const float*)d_in[19];
    const float* bhh_b  = (const float*)d_in[20];
    const float* jk_w   = (const float*)d_in[21];
    // d_in[22] = jk_b: constant across L -> softmax-invariant, unused
    const float* m1_w   = (const float*)d_in[23];
    const float* m1_b   = (const float*)d_in[24];
    const float* m2_w   = (const float*)d_in[25];
    const float* m2_b   = (const float*)d_in[26];
    const float* res_w  = (const float*)d_in[27];
    const float* res_b  = (const float*)d_in[28];
    float* out = (float*)d_out;

    const int* src = ei;
    const int* dst = ei + cE;

    // ---------------- workspace layout (~91 MB base) ----------------
    char* ws = (char*)d_ws;
    size_t off = 0;
    auto alloc = [&](size_t bytes) -> char* {
        size_t o = (off + 255) & ~(size_t)255;
        off = o + bytes;
        return ws + o;
    };
    unsigned short* x16     = (unsigned short*)alloc((size_t)cN * cFin * 2);
    unsigned short* embWT   = (unsigned short*)alloc((size_t)cC * cFin * 2);
    unsigned short* emb_b16 = (unsigned short*)alloc((size_t)cN * cC * 2);
    unsigned short* seqb16  = (unsigned short*)alloc((size_t)cL * cN * cC * 2);
    unsigned short* WT      = (unsigned short*)alloc((size_t)cL * 1024 * 128 * 2);
    float*          bb      = (float*)alloc((size_t)cL * 1024 * 4);
    unsigned short* WihPfb  = (unsigned short*)alloc((size_t)cP * cC * 2);   // fwd rows 0..1279, bwd 1280..2559
    unsigned short* WhhPf   = (unsigned short*)alloc((size_t)c4HL * cHL * 2);
    unsigned short* WhhPb   = (unsigned short*)alloc((size_t)c4HL * cHL * 2);
    float*          biasPf  = (float*)alloc((size_t)c4HL * 4);
    float*          biasPb  = (float*)alloc((size_t)c4HL * 4);
    unsigned short* hf0     = (unsigned short*)alloc((size_t)cN * cHL * 2);
    unsigned short* hf1     = (unsigned short*)alloc((size_t)cN * cHL * 2);
    unsigned short* hbk0    = (unsigned short*)alloc((size_t)cN * cHL * 2);
    unsigned short* hbk1    = (unsigned short*)alloc((size_t)cN * cHL * 2);
    float*          cf      = (float*)alloc((size_t)cN * cHL * 4);
    float*          cbk     = (float*)alloc((size_t)cN * cHL * 4);
    float*          jks     = (float*)alloc((size_t)cL * cN * 4);
    float*          pooled  = (float*)alloc((size_t)cG * cC * 4);
    float*          cnt     = (float*)alloc((size_t)cG * 4);
    int*            offs    = (int*)alloc((size_t)(cN + 1) * 4);
    int*            cursor  = (int*)alloc((size_t)cN * 4);
    int*            src_csr = (int*)alloc((size_t)cE * 4);
    unsigned short* xlr     = (unsigned short*)alloc((size_t)cN * 1024 * 2);
    // P (Wih-hoist) allocated LAST; used only if the workspace is big enough.
    unsigned short* Pall    = (unsigned short*)alloc((size_t)cL * cN * cP * 2);  // 256 MB
    const bool useP = (off <= ws_size);

    unsigned short* WihPf = WihPfb;
    unsigned short* WihPb = WihPfb + (size_t)c4HL * cC;

    hipStream_t s = stream;

    // ---------------- CSR by dst (payload = src) ----------------
    fillI(cursor, cN, 0, s);
    hist_kernel<<<ceil_div(cE, 256), 256, 0, s>>>(dst, cursor);
    scan_kernel<<<1, 256, 0, s>>>(cursor, offs);
    copy_i32_kernel<<<ceil_div(cN, 256), 256, 0, s>>>(offs, cursor, cN);
    scatter_kernel<<<ceil_div(cE, 256), 256, 0, s>>>(src, dst, cursor, src_csr);

    // ---------------- weight prep (bf16) ----------------
    wproj_prep_kernel<<<ceil_div((long)cL * 1024 * 128, 256), 256, 0, s>>>(Wl, Wr, WT);
    bias_prep_kernel<<<ceil_div((long)cL * 1024, 256), 256, 0, s>>>(bl, br, bb);
    embw_prep_kernel<<<ceil_div((long)cC * cFin, 256), 256, 0, s>>>(emb_W, embWT);
    convB(x, x16, (long)cN * cFin, s);
    lstm_prep_kernel<<<ceil_div((long)c4HL * 449, 256), 256, 0, s>>>(
        Wih_f, Whh_f, bih_f, bhh_f, WihPf, WhhPf, biasPf);
    lstm_prep_kernel<<<ceil_div((long)c4HL * 449, 256), 256, 0, s>>>(
        Wih_b, Whh_b, bih_b, bhh_b, WihPb, WhhPb, biasPb);
    init_tail_kernel<<<ceil_div((long)cL * cN + cG * cC + cG, 256), 256, 0, s>>>(jks, pooled, cnt);

    // ---------------- embedding (bf16 MFMA, direct bf16 out) ----------------
    launch_mfma<1>(x16, embWT, cFin, nullptr, nullptr, 0, emb_b, emb_b16, cN, cC, s);

    // ---------------- GAT layers ----------------
    for (int l = 0; l < cL; l++) {
        const unsigned short* hin = (l == 0) ? emb_b16 : seqb16 + (size_t)(l - 1) * cN * cC;
        launch_mfma_swz<1, 1>(hin, WT + (size_t)l * 1024 * 128, cC,
                              bb + (size_t)l * 1024, xlr, cN, 1024, s);
        gat_fused_kernel<<<cN / 2, 256, 0, s>>>(
            xlr, src_csr, offs, att_a + (size_t)l * cH * cC,
            conv_b + (size_t)l * cC, ln_w + (size_t)l * cC, ln_b + (size_t)l * cC,
            seqb16 + (size_t)l * cN * cC);
    }

    // ---------------- bidirectional LSTM ----------------
    if (useP) {
        // P = seq_all(50000x128) @ [Wih_f|Wih_b]^T (2560x128), bf16 out
        launch_mfma_swz<0, 1>(seqb16, WihPfb, cC, nullptr, Pall, cL * cN, cP, s);
    }
    unsigned short* hfb[2]  = {hf0, hf1};
    unsigned short* hbb[2]  = {hbk0, hbk1};
    dim3 lg(80 * 10);   // 80 row-groups (padded) x 5 bn x 2 dir, XCD-swizzled
    for (int k = 0; k < cL; k++) {
        int cur = k & 1, prev = cur ^ 1;
        int t = cL - 1 - k;
        const unsigned short* A1f = seqb16 + (size_t)k * cN * cC;
        const unsigned short* A1b = seqb16 + (size_t)t * cN * cC;
        const unsigned short* PfP = Pall + (size_t)k * cN * cP;
        const unsigned short* PbP = Pall + (size_t)t * cN * cP;
        if (useP) {
            if (k == 0)
                gemm_lstm_dual_kernel<1, 1><<<lg, 512, 0, s>>>(
                    nullptr, nullptr, nullptr, nullptr, nullptr, nullptr, nullptr, nullptr,
                    biasPf, biasPb, cf, cbk, hfb[cur], hbb[cur], jk_w,
                    jks + (size_t)k * cN, jks + (size_t)t * cN, PfP, PbP);
            else
                gemm_lstm_dual_kernel<0, 1><<<lg, 512, 0, s>>>(
                    nullptr, nullptr, nullptr, nullptr, hfb[prev], hbb[prev], WhhPf, WhhPb,
                    biasPf, biasPb, cf, cbk, hfb[cur], hbb[cur], jk_w,
                    jks + (size_t)k * cN, jks + (size_t)t * cN, PfP, PbP);
        } else {
            if (k == 0)
                gemm_lstm_dual_kernel<1, 0><<<lg, 512, 0, s>>>(
                    A1f, A1b, WihPf, WihPb, nullptr, nullptr, nullptr, nullptr,
                    biasPf, biasPb, cf, cbk, hfb[cur], hbb[cur], jk_w,
                    jks + (size_t)k * cN, jks + (size_t)t * cN, nullptr, nullptr);
            else
                gemm_lstm_dual_kernel<0, 0><<<lg, 512, 0, s>>>(
                    A1f, A1b, WihPf, WihPb, hfb[prev], hbb[prev], WhhPf, WhhPb,
                    biasPf, biasPb, cf, cbk, hfb[cur], hbb[cur], jk_w,
                    jks + (size_t)k * cN, jks + (size_t)t * cN, nullptr, nullptr);
        }
    }

    // ---------------- JK softmax, pooling, fused head ----------------
    jk_pool_kernel<<<ceil_div((long)cN * 64, 256), 256, 0, s>>>(seqb16, jks, batch, pooled);
    count_kernel<<<ceil_div(cN, 256), 256, 0, s>>>(batch, cnt);
    div_pool_kernel<<<ceil_div((long)cG * 128, 256), 256, 0, s>>>(pooled, cnt);
    head_fused_kernel<<<dim3(ceil_div(cOUT, 256), cG / 4), 256, 0, s>>>(
        pooled, m1_w, m1_b, m2_w, m2_b, res_w, res_b, out);
}

// Round 13
// 673.636 us; speedup vs baseline: 1.0439x; 1.0439x over previous
//
#include <hip/hip_runtime.h>
#include <hip/hip_bf16.h>
#include <math.h>

// Problem constants (from reference)
constexpr int cN   = 10000;
constexpr int cE   = 120000;
constexpr int cFin = 64;
constexpr int cC   = 128;
constexpr int cH   = 4;
constexpr int cL   = 5;
constexpr int cG   = 500;
constexpr int cOUT = 1801;
constexpr int cHL  = 320;          // (L*C)/2
constexpr int c4HL = 4 * cHL;      // 1280

typedef short bf16x8 __attribute__((ext_vector_type(8)));
typedef float f32x4 __attribute__((ext_vector_type(4)));

__device__ inline unsigned short f2b(float x) {
    union { __hip_bfloat16 h; unsigned short u; } cv;
    cv.h = __float2bfloat16(x);
    return cv.u;
}
__device__ inline float b2f(unsigned short u) {
    union { unsigned int i; float f; } cv;
    cv.i = ((unsigned int)u) << 16;
    return cv.f;
}
__device__ inline float fsig(float x)  { return 1.f / (1.f + __expf(-x)); }
__device__ inline float ftanh(float x) { return 1.f - 2.f / (__expf(2.f * x) + 1.f); }

#define GLD16(g, l) __builtin_amdgcn_global_load_lds( \
    (const __attribute__((address_space(1))) unsigned int*)(g), \
    (__attribute__((address_space(3))) unsigned int*)(l), 16, 0, 0)

// ---------------- mega prep kernel: 7 launches -> 1 ----------------
// Ranges (cumulative): wproj | bias | embw | conv-x | lstmprep-f | lstmprep-b
//                      | init(jks,pooled,cnt) | cursor-zero
constexpr long R0 = (long)cL * 1024 * 128;   // 655360
constexpr long R1 = cL * 1024;               // 5120
constexpr long R2 = cC * cFin;               // 8192
constexpr long R3 = (long)cN * cFin;         // 640000
constexpr long R4 = (long)c4HL * 449;        // 574720
constexpr long R5 = (long)c4HL * 449;        // 574720
constexpr long R6 = (long)cL * cN + cG * cC + cG;   // 114500
constexpr long R7 = cN;                      // 10000
constexpr long RT = R0 + R1 + R2 + R3 + R4 + R5 + R6 + R7;

__device__ inline void lstm_prep_elem(long i, const float* Wih, const float* Whh,
                                      const float* bih, const float* bhh,
                                      unsigned short* WihP, unsigned short* WhhP,
                                      float* biasP) {
    int p = (int)(i / 449), c = (int)(i % 449);
    int u = (p >> 6) * 16 + (p & 15);
    int g = (p >> 4) & 3;
    int r = g * cHL + u;
    if (c < cC)       WihP[(size_t)p * cC + c] = f2b(Wih[(size_t)r * cC + c]);
    else if (c < 448) WhhP[(size_t)p * cHL + (c - cC)] = f2b(Whh[(size_t)r * cHL + (c - cC)]);
    else              biasP[p] = bih[r] + bhh[r];
}

__global__ void mega_prep_kernel(
    const float* __restrict__ Wl, const float* __restrict__ Wr, unsigned short* __restrict__ WT,
    const float* __restrict__ bl, const float* __restrict__ br, float* __restrict__ bb,
    const float* __restrict__ emb_W, unsigned short* __restrict__ embWT,
    const float* __restrict__ x, unsigned short* __restrict__ x16,
    const float* __restrict__ Wih_f, const float* __restrict__ Whh_f,
    const float* __restrict__ bih_f, const float* __restrict__ bhh_f,
    unsigned short* __restrict__ WihPf, unsigned short* __restrict__ WhhPf, float* __restrict__ biasPf,
    const float* __restrict__ Wih_b, const float* __restrict__ Whh_b,
    const float* __restrict__ bih_b, const float* __restrict__ bhh_b,
    unsigned short* __restrict__ WihPb, unsigned short* __restrict__ WhhPb, float* __restrict__ biasPb,
    float* __restrict__ jks, float* __restrict__ pooled, float* __restrict__ cnt,
    int* __restrict__ cursor) {
    long i = (long)blockIdx.x * blockDim.x + threadIdx.x;
    if (i < R0) {
        int k = (int)(i & 127);
        int n = (int)((i >> 7) & 1023);
        int l = (int)(i >> 17);
        const float* W = (n < 512) ? Wl : Wr;
        int nn = n & 511;
        WT[i] = f2b(W[(size_t)l * 65536 + (size_t)k * 512 + nn]);
        return;
    }
    i -= R0;
    if (i < R1) {
        int n = (int)(i & 1023), l = (int)(i >> 10);
        bb[i] = (n < 512) ? bl[l * 512 + n] : br[l * 512 + (n - 512)];
        return;
    }
    i -= R1;
    if (i < R2) {
        int k = (int)(i & 63), n = (int)(i >> 6);
        embWT[i] = f2b(emb_W[(size_t)k * cC + n]);
        return;
    }
    i -= R2;
    if (i < R3) { x16[i] = f2b(x[i]); return; }
    i -= R3;
    if (i < R4) { lstm_prep_elem(i, Wih_f, Whh_f, bih_f, bhh_f, WihPf, WhhPf, biasPf); return; }
    i -= R4;
    if (i < R5) { lstm_prep_elem(i, Wih_b, Whh_b, bih_b, bhh_b, WihPb, WhhPb, biasPb); return; }
    i -= R5;
    if (i < R6) {
        if (i < (long)cL * cN) jks[i] = 0.f;
        else if (i < (long)cL * cN + cG * cC) pooled[i - (long)cL * cN] = 0.f;
        else cnt[i - (long)cL * cN - cG * cC] = 0.f;
        return;
    }
    i -= R6;
    if (i < R7) cursor[i] = 0;
}

// ---------------- CSR build (by dst), payload = src node ----------------
__global__ void hist_kernel(const int* __restrict__ dst, int* __restrict__ count) {
    int i = blockIdx.x * blockDim.x + threadIdx.x;
    if (i < cE) atomicAdd(&count[dst[i]], 1);
}
// exclusive scan over count -> offs[cN+1]; also seeds cursor = offs
__global__ void scan_kernel(const int* __restrict__ count, int* __restrict__ offs,
                            int* __restrict__ cursor) {
    __shared__ int part[256];
    const int tid = threadIdx.x;
    const int CH = (cN + 255) / 256;
    int base = tid * CH;
    int s = 0;
    for (int i = 0; i < CH; i++) {
        int idx = base + i;
        if (idx < cN) s += count[idx];
    }
    part[tid] = s;
    __syncthreads();
    for (int d = 1; d < 256; d <<= 1) {
        int v = 0;
        if (tid >= d) v = part[tid - d];
        __syncthreads();
        if (tid >= d) part[tid] += v;
        __syncthreads();
    }
    int prefix = (tid == 0) ? 0 : part[tid - 1];
    for (int i = 0; i < CH; i++) {
        int idx = base + i;
        if (idx < cN) { offs[idx] = prefix; cursor[idx] = prefix; prefix += count[idx]; }
    }
    if (tid == 255) offs[cN] = prefix;
}
__global__ void scatter_kernel(const int* __restrict__ src, const int* __restrict__ dst,
                               int* __restrict__ cursor, int* __restrict__ src_csr) {
    int i = blockIdx.x * blockDim.x + threadIdx.x;
    if (i < cE) {
        int pos = atomicAdd(&cursor[dst[i]], 1);
        src_csr[pos] = src[i];
    }
}

// ---------------- bf16 MFMA GEMM (128x128, 4 waves) ----------------
// SWZ=1: 1D grid, XCD-aware group swizzle.
template<int HASBIAS, int OUTB, int SWZ>
__global__ __launch_bounds__(256)
void gemm_mfma_kernel(const unsigned short* __restrict__ A1, const unsigned short* __restrict__ B1, int k1,
                      const unsigned short* __restrict__ A2, const unsigned short* __restrict__ B2, int k2,
                      const float* __restrict__ bias, void* __restrict__ Cout, int M, int N, int nbn) {
    int bm, bn;
    if (SWZ) {
        int bid = blockIdx.x;
        int xcd = bid & 7, j = bid >> 3;
        int g   = (j / nbn) * 8 + xcd;
        bm = g << 7;
        bn = (j % nbn) << 7;
        if (bm >= M) return;   // padded group: whole block exits (pre-barrier)
    } else {
        bm = blockIdx.y << 7;
        bn = blockIdx.x << 7;
    }
    __shared__ unsigned short lds[2][2][128 * 32];
    const int tid  = threadIdx.x;
    const int lane = tid & 63;
    const int wave = tid >> 6;
    const int wr = (wave >> 1) << 6;
    const int wc = (wave & 1) << 6;
    const int ns1 = k1 >> 5, ns2 = k2 >> 5, ns = ns1 + ns2;

    const int lrow = lane >> 2;
    const int lke  = (lane & 3) << 3;

    auto stage = [&](int s, int buf) {
        const unsigned short *Ab, *Bb;
        int stride, koff;
        if (s < ns1) { Ab = A1; Bb = B1; stride = k1; koff = s << 5; }
        else         { Ab = A2; Bb = B2; stride = k2; koff = (s - ns1) << 5; }
#pragma unroll
        for (int r = 0; r < 2; r++) {
            int ch  = wave * 2 + r;
            int row = ch * 16 + lrow;
            int ga  = bm + row; if (ga >= M) ga = M - 1;
            GLD16(Ab + (size_t)ga * stride + koff + lke, &lds[buf][0][ch * 512]);
            GLD16(Bb + (size_t)(bn + row) * stride + koff + lke, &lds[buf][1][ch * 512]);
        }
    };

    f32x4 acc[4][4];
#pragma unroll
    for (int i = 0; i < 4; i++)
#pragma unroll
        for (int j = 0; j < 4; j++) acc[i][j] = (f32x4){0.f, 0.f, 0.f, 0.f};

    stage(0, 0);
    const int ko  = (lane >> 4) << 3;
    const int rla = lane & 15;
    for (int s = 0; s < ns; s++) {
        int buf = s & 1;
        __syncthreads();
        if (s + 1 < ns) stage(s + 1, buf ^ 1);
        bf16x8 af[4], bff[4];
#pragma unroll
        for (int f = 0; f < 4; f++) {
            af[f]  = *(const bf16x8*)&lds[buf][0][(wr + f * 16 + rla) * 32 + ko];
            bff[f] = *(const bf16x8*)&lds[buf][1][(wc + f * 16 + rla) * 32 + ko];
        }
#pragma unroll
        for (int i = 0; i < 4; i++)
#pragma unroll
            for (int j = 0; j < 4; j++)
                acc[i][j] = __builtin_amdgcn_mfma_f32_16x16x32_bf16(af[i], bff[j], acc[i][j], 0, 0, 0);
    }

#pragma unroll
    for (int i = 0; i < 4; i++) {
#pragma unroll
        for (int v = 0; v < 4; v++) {
            int m = bm + wr + i * 16 + ((lane >> 4) << 2) + v;
            if (m < M) {
#pragma unroll
                for (int j = 0; j < 4; j++) {
                    int n = bn + wc + j * 16 + rla;
                    float val = acc[i][j][v];
                    if (HASBIAS) val += bias[n];
                    if (OUTB) ((unsigned short*)Cout)[(size_t)m * N + n] = f2b(val);
                    else      ((float*)Cout)[(size_t)m * N + n] = val;
                }
            }
        }
    }
}

// ---------------- dual-direction LSTM step: 128x256 tile, 8 waves -----------
// Grid 800: bid -> xcd=bid&7, jj=bid>>3; g=(jj/10)*8+xcd (row panel, padded
// to 80); inner=jj%10 -> bn=(inner%5)*256, z=inner/5 (direction).
// Gate-interleaved cols: lane's j=0..3 are gates i,f,g,o of unit
// u = ((bn+wc)>>6)*16 + rla.
template<int FIRST>
__global__ __launch_bounds__(512)
void gemm_lstm_dual_kernel(const unsigned short* __restrict__ A1f, const unsigned short* __restrict__ A1b,
                           const unsigned short* __restrict__ Bihf, const unsigned short* __restrict__ Bihb,
                           const unsigned short* __restrict__ A2f, const unsigned short* __restrict__ A2b,
                           const unsigned short* __restrict__ Bhhf, const unsigned short* __restrict__ Bhhb,
                           const float* __restrict__ biasPf, const float* __restrict__ biasPb,
                           float* __restrict__ cff, float* __restrict__ cbb,
                           unsigned short* __restrict__ hOutf, unsigned short* __restrict__ hOutb,
                           const float* __restrict__ jkw,
                           float* __restrict__ scoref, float* __restrict__ scoreb) {
    constexpr int M = cN, k1 = cC, k2 = FIRST ? 0 : cHL;
    const int bid = blockIdx.x;
    const int xcd = bid & 7, jj = bid >> 3;
    const int g     = (jj / 10) * 8 + xcd;
    const int inner = jj % 10;
    const int bm = g << 7;
    if (bm >= M) return;                 // padded group: uniform pre-barrier exit
    const int bn = (inner % 5) << 8;     // 0..1024 step 256
    const int z  = inner / 5;

    const unsigned short* A1 = z ? A1b : A1f;
    const unsigned short* B1 = z ? Bihb : Bihf;
    const unsigned short* A2 = z ? A2b : A2f;
    const unsigned short* B2 = z ? Bhhb : Bhhf;
    const float* biasP = z ? biasPb : biasPf;
    float* cbuf = z ? cbb : cff;
    unsigned short* hOut = z ? hOutb : hOutf;
    const float* jkwz = jkw + (z ? cHL : 0);
    float* score_t = z ? scoreb : scoref;

    __shared__ unsigned short ldsA[2][128 * 32];
    __shared__ unsigned short ldsB[2][256 * 32];
    const int tid  = threadIdx.x;
    const int lane = tid & 63;
    const int wave = tid >> 6;           // 0..7
    const int wr = (wave >> 2) << 6;     // 0 or 64
    const int wc = (wave & 3) << 6;      // 0,64,128,192
    const int ns1 = k1 >> 5, ns2 = k2 >> 5, ns = ns1 + ns2;

    const int lrow = lane >> 2;
    const int lke  = (lane & 3) << 3;

    auto stage = [&](int s, int buf) {
        const unsigned short *Ab, *Bb;
        int stride, koff;
        if (s < ns1) { Ab = A1; Bb = B1; stride = k1; koff = s << 5; }
        else         { Ab = A2; Bb = B2; stride = k2; koff = (s - ns1) << 5; }
        {
            int row = wave * 16 + lrow;
            int ga  = bm + row; if (ga >= M) ga = M - 1;
            GLD16(Ab + (size_t)ga * stride + koff + lke, &ldsA[buf][wave * 512]);
        }
#pragma unroll
        for (int r = 0; r < 2; r++) {
            int ch  = wave * 2 + r;
            int row = ch * 16 + lrow;
            GLD16(Bb + (size_t)(bn + row) * stride + koff + lke, &ldsB[buf][ch * 512]);
        }
    };

    f32x4 acc[4][4];
#pragma unroll
    for (int i = 0; i < 4; i++)
#pragma unroll
        for (int j = 0; j < 4; j++) acc[i][j] = (f32x4){0.f, 0.f, 0.f, 0.f};

    stage(0, 0);
    const int ko  = (lane >> 4) << 3;
    const int rla = lane & 15;
    for (int s = 0; s < ns; s++) {
        int buf = s & 1;
        __syncthreads();
        if (s + 1 < ns) stage(s + 1, buf ^ 1);
        bf16x8 af[4], bff[4];
#pragma unroll
        for (int f = 0; f < 4; f++) {
            af[f]  = *(const bf16x8*)&ldsA[buf][(wr + f * 16 + rla) * 32 + ko];
            bff[f] = *(const bf16x8*)&ldsB[buf][(wc + f * 16 + rla) * 32 + ko];
        }
#pragma unroll
        for (int i = 0; i < 4; i++)
#pragma unroll
            for (int j = 0; j < 4; j++)
                acc[i][j] = __builtin_amdgcn_mfma_f32_16x16x32_bf16(af[i], bff[j], acc[i][j], 0, 0, 0);
    }

    // gate-fused epilogue (fast sigmoid/tanh via v_exp_f32)
    float bias4[4];
#pragma unroll
    for (int j = 0; j < 4; j++) bias4[j] = biasP[bn + wc + j * 16 + rla];
    const int u = ((bn + wc) >> 6) * 16 + rla;
    const float jw = jkwz[u];

#pragma unroll
    for (int i = 0; i < 4; i++) {
#pragma unroll
        for (int v = 0; v < 4; v++) {
            int m = bm + wr + i * 16 + ((lane >> 4) << 2) + v;
            bool ok = (m < M);                      // uniform across rla group
            float gi = acc[i][0][v] + bias4[0];
            float gf = acc[i][1][v] + bias4[1];
            float gg = acc[i][2][v] + bias4[2];
            float go = acc[i][3][v] + bias4[3];
            float si = fsig(gi);
            float sf = fsig(gf);
            float so = fsig(go);
            float tg = ftanh(gg);
            size_t idx = (size_t)m * cHL + u;
            float cold = (FIRST || !ok) ? 0.f : cbuf[idx];
            float cc = sf * cold + si * tg;
            float hh = so * ftanh(cc);
            if (ok) { cbuf[idx] = cc; hOut[idx] = f2b(hh); }
            float part = ok ? hh * jw : 0.f;
#pragma unroll
            for (int o = 1; o < 16; o <<= 1) part += __shfl_xor(part, o);
            if (rla == 0 && ok) atomicAdd(&score_t[m], part);
        }
    }
}

// ---------------- fused GAT layer: one wave per node, 4-edge unrolled -------
__global__ __launch_bounds__(256)
void gat_fused_kernel(const unsigned short* __restrict__ xlr, const int* __restrict__ src_csr,
                      const int* __restrict__ offs, const float* __restrict__ att,
                      const float* __restrict__ conv_b, const float* __restrict__ lnw,
                      const float* __restrict__ lnb, unsigned short* __restrict__ seqb_l) {
    const int wv   = (blockIdx.x * blockDim.x + threadIdx.x) >> 6;  // node
    const int lane = threadIdx.x & 63;
    if (wv >= cN) return;
    const int h   = lane >> 4;
    const int cb  = (lane & 15) << 3;

    bf16x8 xrv = *(const bf16x8*)&xlr[(size_t)wv * 1024 + 512 + lane * 8];
    float xr[8], av[8];
#pragma unroll
    for (int k = 0; k < 8; k++) {
        xr[k] = b2f((unsigned short)xrv[k]);
        av[k] = att[h * 128 + cb + k];
    }

    float m = -INFINITY, l = 0.f;
    float acc[8];
#pragma unroll
    for (int k = 0; k < 8; k++) acc[k] = 0.f;

    const int beg = offs[wv], end = offs[wv + 1];
    int j = beg;
    // 4-edge pipelined online softmax: 4 gathers in flight, one rescale
    for (; j + 3 < end; j += 4) {
        int s0 = src_csr[j], s1 = src_csr[j + 1], s2 = src_csr[j + 2], s3 = src_csr[j + 3];
        bf16x8 xv0 = *(const bf16x8*)&xlr[(size_t)s0 * 1024 + lane * 8];
        bf16x8 xv1 = *(const bf16x8*)&xlr[(size_t)s1 * 1024 + lane * 8];
        bf16x8 xv2 = *(const bf16x8*)&xlr[(size_t)s2 * 1024 + lane * 8];
        bf16x8 xv3 = *(const bf16x8*)&xlr[(size_t)s3 * 1024 + lane * 8];
        float x0[8], x1[8], x2[8], x3[8];
        float sc0 = 0.f, sc1 = 0.f, sc2 = 0.f, sc3 = 0.f;
#pragma unroll
        for (int k = 0; k < 8; k++) {
            x0[k] = b2f((unsigned short)xv0[k]);
            x1[k] = b2f((unsigned short)xv1[k]);
            x2[k] = b2f((unsigned short)xv2[k]);
            x3[k] = b2f((unsigned short)xv3[k]);
            float v0 = x0[k] + xr[k]; v0 = v0 > 0.f ? v0 : 0.2f * v0;
            float v1 = x1[k] + xr[k]; v1 = v1 > 0.f ? v1 : 0.2f * v1;
            float v2 = x2[k] + xr[k]; v2 = v2 > 0.f ? v2 : 0.2f * v2;
            float v3 = x3[k] + xr[k]; v3 = v3 > 0.f ? v3 : 0.2f * v3;
            sc0 = fmaf(v0, av[k], sc0);
            sc1 = fmaf(v1, av[k], sc1);
            sc2 = fmaf(v2, av[k], sc2);
            sc3 = fmaf(v3, av[k], sc3);
        }
#pragma unroll
        for (int o = 1; o < 16; o <<= 1) {
            sc0 += __shfl_xor(sc0, o);
            sc1 += __shfl_xor(sc1, o);
            sc2 += __shfl_xor(sc2, o);
            sc3 += __shfl_xor(sc3, o);
        }
        float mn = fmaxf(fmaxf(fmaxf(sc0, sc1), fmaxf(sc2, sc3)), m);
        float r  = __expf(m - mn);
        float p0 = __expf(sc0 - mn);
        float p1 = __expf(sc1 - mn);
        float p2 = __expf(sc2 - mn);
        float p3 = __expf(sc3 - mn);
        l = l * r + p0 + p1 + p2 + p3;
#pragma unroll
        for (int k = 0; k < 8; k++)
            acc[k] = fmaf(acc[k], r,
                          fmaf(p0, x0[k], fmaf(p1, x1[k], fmaf(p2, x2[k], p3 * x3[k]))));
        m = mn;
    }
    // 1-3 edge tail
    for (; j < end; j++) {
        int s0 = src_csr[j];
        bf16x8 xv = *(const bf16x8*)&xlr[(size_t)s0 * 1024 + lane * 8];
        float x[8], sc = 0.f;
#pragma unroll
        for (int k = 0; k < 8; k++) {
            x[k] = b2f((unsigned short)xv[k]);
            float v = x[k] + xr[k];
            v = v > 0.f ? v : 0.2f * v;
            sc = fmaf(v, av[k], sc);
        }
#pragma unroll
        for (int o = 1; o < 16; o <<= 1) sc += __shfl_xor(sc, o);
        float mn = fmaxf(m, sc);
        float r  = __expf(m - mn);
        float p  = __expf(sc - mn);
        l = l * r + p;
#pragma unroll
        for (int k = 0; k < 8; k++) acc[k] = fmaf(acc[k], r, p * x[k]);
        m = mn;
    }
    float inv = 1.f / (l + 1e-16f);

#pragma unroll
    for (int k = 0; k < 8; k++) {
        float v = acc[k] * inv;
        v += __shfl_xor(v, 16);
        v += __shfl_xor(v, 32);
        acc[k] = 0.25f * v + conv_b[cb + k];
    }
    float ssum = 0.f;
#pragma unroll
    for (int k = 0; k < 8; k++) ssum += acc[k];
#pragma unroll
    for (int o = 1; o < 16; o <<= 1) ssum += __shfl_xor(ssum, o);
    float mu = ssum * (1.f / 128.f);
    float vs = 0.f;
#pragma unroll
    for (int k = 0; k < 8; k++) { float d = acc[k] - mu; vs = fmaf(d, d, vs); }
#pragma unroll
    for (int o = 1; o < 16; o <<= 1) vs += __shfl_xor(vs, o);
    float rstd = 1.f / sqrtf(vs * (1.f / 128.f) + 1e-5f);

    float outv[8];
#pragma unroll
    for (int k = 0; k < 8; k++)
        outv[k] = (acc[k] - mu) * rstd * lnw[cb + k] + lnb[cb + k];

    if (h == 0) {
        size_t b = (size_t)wv * 128 + cb;
        bf16x8 ob;
#pragma unroll
        for (int k = 0; k < 8; k++) ob[k] = (short)f2b(outv[k]);
        *(bf16x8*)&seqb_l[b] = ob;
    }
}

// ---------------- JK softmax + mean pooling (bf16 seq, fused count) --------
__global__ void jk_pool_kernel(const unsigned short* __restrict__ seqb, const float* __restrict__ score,
                               const int* __restrict__ batch, float* __restrict__ pooled,
                               float* __restrict__ cnt) {
    int wid = (blockIdx.x * blockDim.x + threadIdx.x) >> 6;
    int lane = threadIdx.x & 63;
    if (wid >= cN) return;
    float s[cL], mx = -INFINITY;
#pragma unroll
    for (int l = 0; l < cL; l++) { s[l] = score[(size_t)l * cN + wid]; mx = fmaxf(mx, s[l]); }
    float se = 0.f;
#pragma unroll
    for (int l = 0; l < cL; l++) { s[l] = __expf(s[l] - mx); se += s[l]; }
    float inv = 1.f / se;
    int g = batch[wid];
    float acc0 = 0.f, acc1 = 0.f;
#pragma unroll
    for (int l = 0; l < cL; l++) {
        const unsigned short* sp = seqb + ((size_t)l * cN + wid) * 128;
        float w = s[l] * inv;
        acc0 += w * b2f(sp[lane]);
        acc1 += w * b2f(sp[lane + 64]);
    }
    atomicAdd(&pooled[(size_t)g * 128 + lane], acc0);
    atomicAdd(&pooled[(size_t)g * 128 + lane + 64], acc1);
    if (lane == 0) atomicAdd(&cnt[g], 1.f);
}

// ---------------- fused MLP head (divides pooled by cnt at load) ------------
__global__ __launch_bounds__(256)
void head_fused_kernel(const float* __restrict__ pooled, const float* __restrict__ cnt,
                       const float* __restrict__ m1_w, const float* __restrict__ m1_b,
                       const float* __restrict__ m2_w, const float* __restrict__ m2_b,
                       const float* __restrict__ res_w, const float* __restrict__ res_b,
                       float* __restrict__ out) {
    __shared__ float pl[4][128];
    __shared__ float hd[4][128];
    const int tid = threadIdx.x;
    const int r0 = blockIdx.y << 2;
    const int c0 = blockIdx.x << 8;
#pragma unroll
    for (int e = tid; e < 512; e += 256) {
        int r = e >> 7, k = e & 127;
        float invc = 1.f / fmaxf(cnt[r0 + r], 1.f);
        pl[r][k] = pooled[(size_t)(r0 + r) * 128 + k] * invc;
    }
    __syncthreads();
#pragma unroll
    for (int e = tid; e < 512; e += 256) {
        int r = e >> 7, n = e & 127;
        float acc = m1_b[n];
#pragma unroll 8
        for (int k = 0; k < 128; k++) acc = fmaf(pl[r][k], m1_w[k * 128 + n], acc);
        hd[r][n] = fmaxf(acc, 0.f);
    }
    __syncthreads();
    int col = c0 + tid;
    if (col >= cOUT) return;
    float b = m2_b[col] + res_b[col];
    float acc[4] = {b, b, b, b};
    for (int k = 0; k < 128; k++) {
        float w2 = m2_w[(size_t)k * cOUT + col];
        float wr = res_w[(size_t)k * cOUT + col];
#pragma unroll
        for (int r = 0; r < 4; r++)
            acc[r] = fmaf(hd[r][k], w2, fmaf(pl[r][k], wr, acc[r]));
    }
#pragma unroll
    for (int r = 0; r < 4; r++)
        out[(size_t)(r0 + r) * cOUT + col] = acc[r];
}

// ---------------- launch helpers ----------------
static inline int ceil_div(long a, long b) { return (int)((a + b - 1) / b); }

// non-swizzled (embedding: single column block)
template<int OUTB>
static void launch_mfma(const unsigned short* A1, const unsigned short* B1, int k1,
                        const float* bias, void* C, int M, int N, hipStream_t s) {
    dim3 g((N + 127) >> 7, (M + 127) >> 7);
    gemm_mfma_kernel<1, OUTB, 0><<<g, 256, 0, s>>>(A1, B1, k1, nullptr, nullptr, 0, bias, C, M, N, 0);
}
// XCD-swizzled (nbn column blocks share a row panel)
template<int HASBIAS, int OUTB>
static void launch_mfma_swz(const unsigned short* A1, const unsigned short* B1, int k1,
                            const float* bias, void* C, int M, int N, hipStream_t s) {
    int nbn = N >> 7;
    int groups = ((((M + 127) >> 7) + 7) / 8) * 8;   // pad to multiple of 8
    dim3 g(groups * nbn);
    gemm_mfma_kernel<HASBIAS, OUTB, 1><<<g, 256, 0, s>>>(A1, B1, k1, nullptr, nullptr, 0, bias, C, M, N, nbn);
}

extern "C" void kernel_launch(void* const* d_in, const int* in_sizes, int n_in,
                              void* d_out, int out_size, void* d_ws, size_t ws_size,
                              hipStream_t stream) {
    const float* x      = (const float*)d_in[0];
    const int*   ei     = (const int*)d_in[1];
    const int*   batch  = (const int*)d_in[2];
    const float* emb_W  = (const float*)d_in[3];
    const float* emb_b  = (const float*)d_in[4];
    const float* Wl     = (const float*)d_in[5];
    const float* bl     = (const float*)d_in[6];
    const float* Wr     = (const float*)d_in[7];
    const float* br     = (const float*)d_in[8];
    const float* att_a  = (const float*)d_in[9];
    const float* conv_b = (const float*)d_in[10];
    const float* ln_w   = (const float*)d_in[11];
    const float* ln_b   = (const float*)d_in[12];
    const float* Wih_f  = (const float*)d_in[13];
    const float* Whh_f  = (const float*)d_in[14];
    const float* bih_f  = (const float*)d_in[15];
    const float* bhh_f  = (const float*)d_in[16];
    const float* Wih_b  = (const float*)d_in[17];
    const float* Whh_b  = (const float*)d_in[18];
    const float* bih_b  = (const float*)d_in[19];
    const float* bhh_b  = (const float*)d_in[20];
    const float* jk_w   = (const float*)d_in[21];
    // d_in[22] = jk_b: constant across L -> softmax-invariant, unused
    const float* m1_w   = (const float*)d_in[23];
    const float* m1_b   = (const float*)d_in[24];
    const float* m2_w   = (const float*)d_in[25];
    const float* m2_b   = (const float*)d_in[26];
    const float* res_w  = (const float*)d_in[27];
    const float* res_b  = (const float*)d_in[28];
    float* out = (float*)d_out;

    const int* src = ei;
    const int* dst = ei + cE;

    // ---------------- workspace layout (~66 MB) ----------------
    char* ws = (char*)d_ws;
    size_t off = 0;
    auto alloc = [&](size_t bytes) -> char* {
        size_t o = (off + 255) & ~(size_t)255;
        off = o + bytes;
        return ws + o;
    };
    unsigned short* x16     = (unsigned short*)alloc((size_t)cN * cFin * 2);
    unsigned short* embWT   = (unsigned short*)alloc((size_t)cC * cFin * 2);
    unsigned short* emb_b16 = (unsigned short*)alloc((size_t)cN * cC * 2);
    unsigned short* seqb16  = (unsigned short*)alloc((size_t)cL * cN * cC * 2);
    unsigned short* WT      = (unsigned short*)alloc((size_t)cL * 1024 * 128 * 2);
    float*          bb      = (float*)alloc((size_t)cL * 1024 * 4);
    unsigned short* WihPf   = (unsigned short*)alloc((size_t)c4HL * cC * 2);
    unsigned short* WihPb   = (unsigned short*)alloc((size_t)c4HL * cC * 2);
    unsigned short* WhhPf   = (unsigned short*)alloc((size_t)c4HL * cHL * 2);
    unsigned short* WhhPb   = (unsigned short*)alloc((size_t)c4HL * cHL * 2);
    float*          biasPf  = (float*)alloc((size_t)c4HL * 4);
    float*          biasPb  = (float*)alloc((size_t)c4HL * 4);
    unsigned short* hf0     = (unsigned short*)alloc((size_t)cN * cHL * 2);
    unsigned short* hf1     = (unsigned short*)alloc((size_t)cN * cHL * 2);
    unsigned short* hbk0    = (unsigned short*)alloc((size_t)cN * cHL * 2);
    unsigned short* hbk1    = (unsigned short*)alloc((size_t)cN * cHL * 2);
    float*          cf      = (float*)alloc((size_t)cN * cHL * 4);
    float*          cbk     = (float*)alloc((size_t)cN * cHL * 4);
    float*          jks     = (float*)alloc((size_t)cL * cN * 4);
    float*          pooled  = (float*)alloc((size_t)cG * cC * 4);
    float*          cnt     = (float*)alloc((size_t)cG * 4);
    int*            offs    = (int*)alloc((size_t)(cN + 1) * 4);
    int*            cursor  = (int*)alloc((size_t)cN * 4);
    int*            src_csr = (int*)alloc((size_t)cE * 4);
    unsigned short* xlr     = (unsigned short*)alloc((size_t)cN * 1024 * 2);

    hipStream_t s = stream;

    // ---------------- mega prep (7 launches -> 1; also zeroes cursor) -------
    mega_prep_kernel<<<ceil_div(RT, 256), 256, 0, s>>>(
        Wl, Wr, WT, bl, br, bb, emb_W, embWT, x, x16,
        Wih_f, Whh_f, bih_f, bhh_f, WihPf, WhhPf, biasPf,
        Wih_b, Whh_b, bih_b, bhh_b, WihPb, WhhPb, biasPb,
        jks, pooled, cnt, cursor);

    // ---------------- CSR by dst (payload = src) ----------------
    hist_kernel<<<ceil_div(cE, 256), 256, 0, s>>>(dst, cursor);
    scan_kernel<<<1, 256, 0, s>>>(cursor, offs, cursor);
    scatter_kernel<<<ceil_div(cE, 256), 256, 0, s>>>(src, dst, cursor, src_csr);

    // ---------------- embedding (bf16 MFMA, direct bf16 out) ----------------
    launch_mfma<1>(x16, embWT, cFin, emb_b, emb_b16, cN, cC, s);

    // ---------------- GAT layers ----------------
    for (int l = 0; l < cL; l++) {
        const unsigned short* hin = (l == 0) ? emb_b16 : seqb16 + (size_t)(l - 1) * cN * cC;
        launch_mfma_swz<1, 1>(hin, WT + (size_t)l * 1024 * 128, cC,
                              bb + (size_t)l * 1024, xlr, cN, 1024, s);
        gat_fused_kernel<<<ceil_div((long)cN * 64, 256), 256, 0, s>>>(
            xlr, src_csr, offs, att_a + (size_t)l * cH * cC,
            conv_b + (size_t)l * cC, ln_w + (size_t)l * cC, ln_b + (size_t)l * cC,
            seqb16 + (size_t)l * cN * cC);
    }

    // ---------------- bidirectional LSTM (both directions per launch) -------
    unsigned short* hfb[2]  = {hf0, hf1};
    unsigned short* hbb[2]  = {hbk0, hbk1};
    dim3 lg(80 * 10);   // 80 row-groups (padded) x 5 bn x 2 dir, XCD-swizzled
    for (int k = 0; k < cL; k++) {
        int cur = k & 1, prev = cur ^ 1;
        int t = cL - 1 - k;
        const unsigned short* A1f = seqb16 + (size_t)k * cN * cC;
        const unsigned short* A1b = seqb16 + (size_t)t * cN * cC;
        if (k == 0)
            gemm_lstm_dual_kernel<1><<<lg, 512, 0, s>>>(
                A1f, A1b, WihPf, WihPb, nullptr, nullptr, nullptr, nullptr,
                biasPf, biasPb, cf, cbk, hfb[cur], hbb[cur], jk_w,
                jks, jks + (size_t)t * cN);
        else
            gemm_lstm_dual_kernel<0><<<lg, 512, 0, s>>>(
                A1f, A1b, WihPf, WihPb, hfb[prev], hbb[prev], WhhPf, WhhPb,
                biasPf, biasPb, cf, cbk, hfb[cur], hbb[cur], jk_w,
                jks + (size_t)k * cN, jks + (size_t)t * cN);
    }

    // ---------------- JK softmax + pooling (+count), fused head (+div) ------
    jk_pool_kernel<<<ceil_div((long)cN * 64, 256), 256, 0, s>>>(seqb16, jks, batch, pooled, cnt);
    head_fused_kernel<<<dim3(ceil_div(cOUT, 256), cG / 4), 256, 0, s>>>(
        pooled, cnt, m1_w, m1_b, m2_w, m2_b, res_w, res_b, out);
}